// Round 2
// baseline (154.461 us; speedup 1.0000x reference)
//
#include <hip/hip_runtime.h>
#include <hip/hip_bf16.h>

#define NN   2048
#define DDIM 128
#define HH   8
#define DHH  16
#define NEDGE 65536
#define FFN  512
#define EPSV 1e-5f
#define CAP  512

typedef const float* fp_c;

// ---------------- detect int64 vs int32 index layout ----------------
// If src is int64 (values < 2048), odd int32 words are all 0.
__global__ void k_detect(int* flag, const int* src) {
    if (threadIdx.x == 0 && blockIdx.x == 0) {
        int all0 = 1;
        for (int k = 1; k < 64; k += 2) all0 &= (src[k] == 0);
        *flag = all0;  // 1 => int64 layout
    }
}

// ---------------- eid init: -2 = masked ----------------
__global__ void k_init(int* eid) {
    int idx = blockIdx.x * blockDim.x + threadIdx.x;
    int4 v = make_int4(-2, -2, -2, -2);
    int total = NN * NN / 4;
    for (int i = idx; i < total; i += gridDim.x * blockDim.x)
        ((int4*)eid)[i] = v;
}

// ---------------- scatter edges: max-e last-wins; -1 = adjacent no-bias ----------------
__global__ void k_scatter(int* eid, const int* src, const int* dst, const int* flag) {
    int is64 = *flag;
    int e = blockIdx.x * blockDim.x + threadIdx.x;
    if (e < NEDGE) {
        int s = is64 ? src[2 * e] : src[e];
        int d = is64 ? dst[2 * e] : dst[e];
        atomicMax(&eid[s * NN + d], e);
        atomicMax(&eid[d * NN + s], -1);
    } else if (e < NEDGE + NN) {
        int i = e - NEDGE;
        atomicMax(&eid[i * NN + i], -1);
    }
}

// ---------------- edge bias: eb[e][h] = edge_feat[e,:10] @ We + be ----------------
__global__ void k_ebias(float* eb, fp_c edge_feat, fp_c We, fp_c be) {
    __shared__ float sWe[80];
    __shared__ float sbe[8];
    if (threadIdx.x < 80) sWe[threadIdx.x] = We[threadIdx.x];
    if (threadIdx.x < 8)  sbe[threadIdx.x] = be[threadIdx.x];
    __syncthreads();
    int e = blockIdx.x * blockDim.x + threadIdx.x;
    if (e >= NEDGE) return;
    float ef[10];
#pragma unroll
    for (int k = 0; k < 10; k++) ef[k] = edge_feat[e * 10 + k];
#pragma unroll
    for (int h = 0; h < 8; h++) {
        float a = sbe[h];
#pragma unroll
        for (int k = 0; k < 10; k++) a += ef[k] * sWe[k * 8 + h];
        eb[e * 8 + h] = a;
    }
}

// ---------------- QKV projections (Q pre-scaled by 0.25 = 1/sqrt(DH)) ----------------
template<int ROWS>
__global__ __launch_bounds__(128) void k_qkv(float* Qf, float* Kf, float* Vf, fp_c x,
                                             fp_c Wq, fp_c bq, fp_c Wk, fp_c bk, fp_c Wv, fp_c bv) {
    __shared__ float sx[ROWS][DDIM];
    int c = threadIdx.x;
    int r0 = blockIdx.x * ROWS;
#pragma unroll
    for (int r = 0; r < ROWS; r++) sx[r][c] = x[(r0 + r) * DDIM + c];
    __syncthreads();
    float aq[ROWS], ak[ROWS], av[ROWS];
#pragma unroll
    for (int r = 0; r < ROWS; r++) { aq[r] = 0; ak[r] = 0; av[r] = 0; }
    for (int k = 0; k < DDIM; k++) {
        float wq = Wq[k * DDIM + c];
        float wk = Wk[k * DDIM + c];
        float wv = Wv[k * DDIM + c];
#pragma unroll
        for (int r = 0; r < ROWS; r++) {
            float xv = sx[r][k];
            aq[r] += xv * wq; ak[r] += xv * wk; av[r] += xv * wv;
        }
    }
    float vbq = bq[c], vbk = bk[c], vbv = bv[c];
#pragma unroll
    for (int r = 0; r < ROWS; r++) {
        Qf[(r0 + r) * DDIM + c] = (aq[r] + vbq) * 0.25f;
        Kf[(r0 + r) * DDIM + c] = ak[r] + vbk;
        Vf[(r0 + r) * DDIM + c] = av[r] + vbv;
    }
}

// ---------------- sparse masked attention: one wave per query row ----------------
__global__ __launch_bounds__(64) void k_attn(float* attn_out, const float* Qf, const float* Kf,
                                             const float* Vf, const int* eid, const float* eb) {
    __shared__ float qrow[DDIM];
    __shared__ int   lj[CAP];
    __shared__ int   lev[CAP];
    __shared__ float sc[CAP][HH];
    __shared__ float hinv[HH];
    int i = blockIdx.x;
    int lane = threadIdx.x;
    qrow[lane]      = Qf[i * DDIM + lane];
    qrow[lane + 64] = Qf[i * DDIM + lane + 64];

    // phase 1: scan eid row, compact neighbors (deterministic, j-ascending)
    int cnt = 0;
    const int* erow = eid + (long)i * NN;
    for (int base = 0; base < NN; base += 64) {
        int v = erow[base + lane];
        bool pred = (v >= -1);
        unsigned long long mask = __ballot(pred);
        int pos = __popcll(mask & ((1ull << lane) - 1ull));
        if (pred && (cnt + pos) < CAP) { lj[cnt + pos] = base + lane; lev[cnt + pos] = v; }
        cnt += __popcll(mask);
    }
    if (cnt > CAP) cnt = CAP;
    __syncthreads();

    // phase 2: scores (lane = nsub*8 + h)
    int h = lane & 7;
    int nsub = lane >> 3;
    for (int n0 = 0; n0 < cnt; n0 += 8) {
        int n = n0 + nsub;
        if (n < cnt) {
            int j = lj[n];
            const float* krow = Kf + j * DDIM + h * DHH;
            const float* q = qrow + h * DHH;
            float s = 0.f;
#pragma unroll
            for (int d = 0; d < DHH; d++) s += q[d] * krow[d];
            int ev = lev[n];
            if (ev >= 0) s += eb[ev * 8 + h];
            sc[n][h] = s;
        }
    }
    __syncthreads();

    // phase 3: per-head softmax (8 contiguous lanes per head)
    {
        int hh = lane >> 3;
        int sub = lane & 7;
        float m = -1e30f;
        for (int n = sub; n < cnt; n += 8) m = fmaxf(m, sc[n][hh]);
#pragma unroll
        for (int off = 1; off < 8; off <<= 1) m = fmaxf(m, __shfl_xor(m, off));
        float ssum = 0.f;
        for (int n = sub; n < cnt; n += 8) {
            float e = __expf(sc[n][hh] - m);
            sc[n][hh] = e;
            ssum += e;
        }
#pragma unroll
        for (int off = 1; off < 8; off <<= 1) ssum += __shfl_xor(ssum, off);
        if (sub == 0) hinv[hh] = 1.0f / ssum;
    }
    __syncthreads();

    // phase 4: PV — coalesced V rows
    int c0 = lane, c1 = lane + 64;
    int h0 = c0 >> 4, h1 = c1 >> 4;
    float a0 = 0.f, a1 = 0.f;
    for (int n = 0; n < cnt; n++) {
        int j = lj[n];
        const float* vrow = Vf + j * DDIM;
        a0 += sc[n][h0] * vrow[c0];
        a1 += sc[n][h1] * vrow[c1];
    }
    attn_out[i * DDIM + c0] = a0 * hinv[h0];
    attn_out[i * DDIM + c1] = a1 * hinv[h1];
}

// ---------------- Wo proj + bias + residual + LN1 ----------------
template<int ROWS>
__global__ __launch_bounds__(128) void k_proj_ln(float* x1, const float* ain, fp_c Wo, fp_c bo,
                                                 fp_c node, fp_c g1, fp_c b1) {
    __shared__ float sa[ROWS][DDIM];
    __shared__ float2 scratch[2];
    int c = threadIdx.x;
    int r0 = blockIdx.x * ROWS;
#pragma unroll
    for (int r = 0; r < ROWS; r++) sa[r][c] = ain[(r0 + r) * DDIM + c];
    __syncthreads();
    float acc[ROWS];
#pragma unroll
    for (int r = 0; r < ROWS; r++) acc[r] = 0.f;
    for (int k = 0; k < DDIM; k++) {
        float w = Wo[k * DDIM + c];
#pragma unroll
        for (int r = 0; r < ROWS; r++) acc[r] += sa[r][k] * w;
    }
    float bov = bo[c];
    float gv = g1[c], bv = b1[c];
    for (int r = 0; r < ROWS; r++) {
        float val = acc[r] + bov + node[(r0 + r) * DDIM + c];
        float2 v; v.x = val; v.y = val * val;
#pragma unroll
        for (int off = 32; off >= 1; off >>= 1) {
            v.x += __shfl_down(v.x, off);
            v.y += __shfl_down(v.y, off);
        }
        if ((c & 63) == 0) scratch[c >> 6] = v;
        __syncthreads();
        float sum = scratch[0].x + scratch[1].x;
        float sumsq = scratch[0].y + scratch[1].y;
        __syncthreads();
        float mu = sum * (1.0f / DDIM);
        float var = sumsq * (1.0f / DDIM) - mu * mu;
        x1[(r0 + r) * DDIM + c] = (val - mu) * rsqrtf(var + EPSV) * gv + bv;
    }
}

// ---------------- FFN layer 1: relu(x1 @ W1 + bf1) ----------------
template<int ROWS>
__global__ __launch_bounds__(256) void k_ffn1(float* hidden, const float* x1, fp_c W1, fp_c bf1) {
    __shared__ float sx[ROWS][DDIM];
    int t = threadIdx.x;
    int r0 = blockIdx.x * ROWS;
    for (int idx = t; idx < ROWS * DDIM; idx += 256)
        sx[idx / DDIM][idx % DDIM] = x1[r0 * DDIM + idx];
    __syncthreads();
    int c0 = t, c1 = t + 256;
    float a0[ROWS], a1[ROWS];
#pragma unroll
    for (int r = 0; r < ROWS; r++) { a0[r] = 0.f; a1[r] = 0.f; }
    for (int k = 0; k < DDIM; k++) {
        float w0 = W1[k * FFN + c0];
        float w1 = W1[k * FFN + c1];
#pragma unroll
        for (int r = 0; r < ROWS; r++) {
            float xv = sx[r][k];
            a0[r] += xv * w0; a1[r] += xv * w1;
        }
    }
    float b0 = bf1[c0], b1v = bf1[c1];
#pragma unroll
    for (int r = 0; r < ROWS; r++) {
        hidden[(r0 + r) * FFN + c0] = fmaxf(a0[r] + b0, 0.f);
        hidden[(r0 + r) * FFN + c1] = fmaxf(a1[r] + b1v, 0.f);
    }
}

// ---------------- FFN layer 2 + residual + LN2 -> f32 out ----------------
template<int ROWS>
__global__ __launch_bounds__(128) void k_ffn2_ln(float* out, const float* hidden,
                                                 const float* x1, fp_c W2, fp_c bf2, fp_c g2, fp_c b2) {
    __shared__ float sh[ROWS][FFN];
    __shared__ float2 scratch[2];
    int c = threadIdx.x;
    int r0 = blockIdx.x * ROWS;
    for (int idx = c; idx < ROWS * FFN; idx += 128)
        sh[idx / FFN][idx % FFN] = hidden[r0 * FFN + idx];
    __syncthreads();
    float acc[ROWS];
#pragma unroll
    for (int r = 0; r < ROWS; r++) acc[r] = 0.f;
    for (int k = 0; k < FFN; k++) {
        float w = W2[k * DDIM + c];
#pragma unroll
        for (int r = 0; r < ROWS; r++) acc[r] += sh[r][k] * w;
    }
    float bv2 = bf2[c];
    float gv = g2[c], bbv = b2[c];
    for (int r = 0; r < ROWS; r++) {
        float val = acc[r] + bv2 + x1[(r0 + r) * DDIM + c];
        float2 v; v.x = val; v.y = val * val;
#pragma unroll
        for (int off = 32; off >= 1; off >>= 1) {
            v.x += __shfl_down(v.x, off);
            v.y += __shfl_down(v.y, off);
        }
        if ((c & 63) == 0) scratch[c >> 6] = v;
        __syncthreads();
        float sum = scratch[0].x + scratch[1].x;
        float sumsq = scratch[0].y + scratch[1].y;
        __syncthreads();
        float mu = sum * (1.0f / DDIM);
        float var = sumsq * (1.0f / DDIM) - mu * mu;
        out[(r0 + r) * DDIM + c] = (val - mu) * rsqrtf(var + EPSV) * gv + bbv;
    }
}

extern "C" void kernel_launch(void* const* d_in, const int* in_sizes, int n_in,
                              void* d_out, int out_size, void* d_ws, size_t ws_size,
                              hipStream_t stream) {
    fp_c node = (fp_c)d_in[0];
    fp_c edge_feat = (fp_c)d_in[1];
    const int* src = (const int*)d_in[2];
    const int* dst = (const int*)d_in[3];
    fp_c Wq = (fp_c)d_in[4];  fp_c bq = (fp_c)d_in[5];
    fp_c Wk = (fp_c)d_in[6];  fp_c bk = (fp_c)d_in[7];
    fp_c Wv = (fp_c)d_in[8];  fp_c bv = (fp_c)d_in[9];
    fp_c Wo = (fp_c)d_in[10]; fp_c bo = (fp_c)d_in[11];
    fp_c We = (fp_c)d_in[12]; fp_c be = (fp_c)d_in[13];
    fp_c g1 = (fp_c)d_in[14]; fp_c b1n = (fp_c)d_in[15];
    fp_c g2 = (fp_c)d_in[16]; fp_c b2n = (fp_c)d_in[17];
    fp_c W1 = (fp_c)d_in[18]; fp_c bf1 = (fp_c)d_in[19];
    fp_c W2 = (fp_c)d_in[20]; fp_c bf2 = (fp_c)d_in[21];

    char* ws = (char*)d_ws;
    int* flag     = (int*)ws;   ws += 16;
    int* eid      = (int*)ws;   ws += (size_t)NN * NN * 4;
    float* eb     = (float*)ws; ws += (size_t)NEDGE * 8 * 4;
    float* Qf     = (float*)ws; ws += (size_t)NN * DDIM * 4;
    float* Kf     = (float*)ws; ws += (size_t)NN * DDIM * 4;
    float* Vf     = (float*)ws; ws += (size_t)NN * DDIM * 4;
    float* attn_o = (float*)ws; ws += (size_t)NN * DDIM * 4;
    float* x1     = (float*)ws; ws += (size_t)NN * DDIM * 4;
    float* hidden = (float*)ws; ws += (size_t)NN * FFN * 4;

    k_detect<<<1, 64, 0, stream>>>(flag, src);
    k_init<<<2048, 256, 0, stream>>>(eid);
    k_scatter<<<(NEDGE + NN + 255) / 256, 256, 0, stream>>>(eid, src, dst, flag);
    k_ebias<<<NEDGE / 256, 256, 0, stream>>>(eb, edge_feat, We, be);
    k_qkv<8><<<NN / 8, DDIM, 0, stream>>>(Qf, Kf, Vf, node, Wq, bq, Wk, bk, Wv, bv);
    k_attn<<<NN, 64, 0, stream>>>(attn_o, Qf, Kf, Vf, eid, eb);
    k_proj_ln<8><<<NN / 8, DDIM, 0, stream>>>(x1, attn_o, Wo, bo, node, g1, b1n);
    k_ffn1<8><<<NN / 8, 256, 0, stream>>>(hidden, x1, W1, bf1);
    k_ffn2_ln<8><<<NN / 8, DDIM, 0, stream>>>((float*)d_out, hidden, x1, W2, bf2, g2, b2n);
}

// Round 3
// 117.285 us; speedup vs baseline: 1.3170x; 1.3170x over previous
//
#include <hip/hip_runtime.h>
#include <hip/hip_bf16.h>

#define NN   2048
#define DDIM 128
#define HH   8
#define DHH  16
#define NEDGE 65536
#define FFN  512
#define EPSV 1e-5f
#define CAP  512

typedef const float* fp_c;

// ---------------- detect int64 vs int32 index layout ----------------
__global__ void k_detect(int* flag, const int* src) {
    if (threadIdx.x == 0 && blockIdx.x == 0) {
        int all0 = 1;
        for (int k = 1; k < 64; k += 2) all0 &= (src[k] == 0);
        *flag = all0;  // 1 => int64 layout
    }
}

// ---------------- eid init: -2 = masked ----------------
__global__ void k_init(int* eid) {
    int idx = blockIdx.x * blockDim.x + threadIdx.x;
    int4 v = make_int4(-2, -2, -2, -2);
    int total = NN * NN / 4;
    for (int i = idx; i < total; i += gridDim.x * blockDim.x)
        ((int4*)eid)[i] = v;
}

// ---------------- scatter edges: max-e last-wins; -1 = adjacent no-bias ----------------
__global__ void k_scatter(int* eid, const int* src, const int* dst, const int* flag) {
    int is64 = *flag;
    int e = blockIdx.x * blockDim.x + threadIdx.x;
    if (e < NEDGE) {
        int s = is64 ? src[2 * e] : src[e];
        int d = is64 ? dst[2 * e] : dst[e];
        atomicMax(&eid[s * NN + d], e);
        atomicMax(&eid[d * NN + s], -1);
    } else if (e < NEDGE + NN) {
        int i = e - NEDGE;
        atomicMax(&eid[i * NN + i], -1);
    }
}

// ---------------- edge bias: eb[e][h] = edge_feat[e,:10] @ We + be ----------------
__global__ void k_ebias(float* eb, fp_c edge_feat, fp_c We, fp_c be) {
    __shared__ float sWe[80];
    __shared__ float sbe[8];
    if (threadIdx.x < 80) sWe[threadIdx.x] = We[threadIdx.x];
    if (threadIdx.x < 8)  sbe[threadIdx.x] = be[threadIdx.x];
    __syncthreads();
    int e = blockIdx.x * blockDim.x + threadIdx.x;
    if (e >= NEDGE) return;
    float ef[10];
#pragma unroll
    for (int k = 0; k < 10; k++) ef[k] = edge_feat[e * 10 + k];
#pragma unroll
    for (int h = 0; h < 8; h++) {
        float a = sbe[h];
#pragma unroll
        for (int k = 0; k < 10; k++) a += ef[k] * sWe[k * 8 + h];
        eb[e * 8 + h] = a;
    }
}

// ================= high-occupancy dense kernels =================
// All: 512 threads (8 waves), R=4 rows/block, grid 512 blocks -> 32 waves/CU.
// K-split 4-way across thread groups (ks = t>>7), fixed-order LDS reduce.

// ---------------- QKV: node[2048,128] @ {Wq,Wk,Wv}[128,128] ----------------
__global__ __launch_bounds__(512) void k_qkv(float* Qf, float* Kf, float* Vf, fp_c x,
                                             fp_c Wq, fp_c bq, fp_c Wk, fp_c bk, fp_c Wv, fp_c bv) {
    __shared__ float sx[4][DDIM];
    __shared__ float red[3][4][4][DDIM];
    int t = threadIdx.x;
    int r0 = blockIdx.x * 4;
    int c = t & 127;
    int ks = t >> 7;
    sx[t >> 7][t & 127] = x[r0 * DDIM + t];
    __syncthreads();
    float aq[4] = {0, 0, 0, 0}, ak[4] = {0, 0, 0, 0}, av[4] = {0, 0, 0, 0};
    int kbeg = ks * 32;
#pragma unroll 8
    for (int k = kbeg; k < kbeg + 32; k++) {
        float wq = Wq[k * DDIM + c];
        float wk = Wk[k * DDIM + c];
        float wv = Wv[k * DDIM + c];
#pragma unroll
        for (int r = 0; r < 4; r++) {
            float xv = sx[r][k];
            aq[r] += xv * wq; ak[r] += xv * wk; av[r] += xv * wv;
        }
    }
#pragma unroll
    for (int r = 0; r < 4; r++) {
        red[0][ks][r][c] = aq[r];
        red[1][ks][r][c] = ak[r];
        red[2][ks][r][c] = av[r];
    }
    __syncthreads();
    int rr = t >> 7, cc = t & 127;
    float vq = 0, vk = 0, vv = 0;
#pragma unroll
    for (int s = 0; s < 4; s++) {
        vq += red[0][s][rr][cc];
        vk += red[1][s][rr][cc];
        vv += red[2][s][rr][cc];
    }
    Qf[(r0 + rr) * DDIM + cc] = (vq + bq[cc]) * 0.25f;
    Kf[(r0 + rr) * DDIM + cc] = vk + bk[cc];
    Vf[(r0 + rr) * DDIM + cc] = vv + bv[cc];
}

// ---------------- sparse masked attention: one wave per query row ----------------
__global__ __launch_bounds__(64) void k_attn(float* attn_out, const float* Qf, const float* Kf,
                                             const float* Vf, const int* eid, const float* eb) {
    __shared__ float qrow[DDIM];
    __shared__ int   lj[CAP];
    __shared__ int   lev[CAP];
    __shared__ float sc[CAP][HH];
    __shared__ float hinv[HH];
    int i = blockIdx.x;
    int lane = threadIdx.x;
    qrow[lane]      = Qf[i * DDIM + lane];
    qrow[lane + 64] = Qf[i * DDIM + lane + 64];

    int cnt = 0;
    const int* erow = eid + (long)i * NN;
    for (int base = 0; base < NN; base += 64) {
        int v = erow[base + lane];
        bool pred = (v >= -1);
        unsigned long long mask = __ballot(pred);
        int pos = __popcll(mask & ((1ull << lane) - 1ull));
        if (pred && (cnt + pos) < CAP) { lj[cnt + pos] = base + lane; lev[cnt + pos] = v; }
        cnt += __popcll(mask);
    }
    if (cnt > CAP) cnt = CAP;
    __syncthreads();

    int h = lane & 7;
    int nsub = lane >> 3;
    for (int n0 = 0; n0 < cnt; n0 += 8) {
        int n = n0 + nsub;
        if (n < cnt) {
            int j = lj[n];
            const float* krow = Kf + j * DDIM + h * DHH;
            const float* q = qrow + h * DHH;
            float s = 0.f;
#pragma unroll
            for (int d = 0; d < DHH; d++) s += q[d] * krow[d];
            int ev = lev[n];
            if (ev >= 0) s += eb[ev * 8 + h];
            sc[n][h] = s;
        }
    }
    __syncthreads();

    {
        int hh = lane >> 3;
        int sub = lane & 7;
        float m = -1e30f;
        for (int n = sub; n < cnt; n += 8) m = fmaxf(m, sc[n][hh]);
#pragma unroll
        for (int off = 1; off < 8; off <<= 1) m = fmaxf(m, __shfl_xor(m, off));
        float ssum = 0.f;
        for (int n = sub; n < cnt; n += 8) {
            float e = __expf(sc[n][hh] - m);
            sc[n][hh] = e;
            ssum += e;
        }
#pragma unroll
        for (int off = 1; off < 8; off <<= 1) ssum += __shfl_xor(ssum, off);
        if (sub == 0) hinv[hh] = 1.0f / ssum;
    }
    __syncthreads();

    int c0 = lane, c1 = lane + 64;
    int h0 = c0 >> 4, h1 = c1 >> 4;
    float a0 = 0.f, a1 = 0.f;
    for (int n = 0; n < cnt; n++) {
        int j = lj[n];
        const float* vrow = Vf + j * DDIM;
        a0 += sc[n][h0] * vrow[c0];
        a1 += sc[n][h1] * vrow[c1];
    }
    attn_out[i * DDIM + c0] = a0 * hinv[h0];
    attn_out[i * DDIM + c1] = a1 * hinv[h1];
}

// ---------------- Wo proj + bias + residual + LN1 ----------------
__global__ __launch_bounds__(512) void k_proj_ln(float* x1, const float* ain, fp_c Wo, fp_c bo,
                                                 fp_c node, fp_c g1, fp_c b1) {
    __shared__ float sx[4][DDIM];
    __shared__ float red[4][4][DDIM];
    __shared__ float2 sc2[8];
    int t = threadIdx.x;
    int r0 = blockIdx.x * 4;
    int c = t & 127;
    int ks = t >> 7;
    sx[t >> 7][t & 127] = ain[r0 * DDIM + t];
    __syncthreads();
    float acc[4] = {0, 0, 0, 0};
    int kbeg = ks * 32;
#pragma unroll 8
    for (int k = kbeg; k < kbeg + 32; k++) {
        float w = Wo[k * DDIM + c];
#pragma unroll
        for (int r = 0; r < 4; r++) acc[r] += sx[r][k] * w;
    }
#pragma unroll
    for (int r = 0; r < 4; r++) red[ks][r][c] = acc[r];
    __syncthreads();
    int rr = t >> 7, cc = t & 127;
    float val = red[0][rr][cc] + red[1][rr][cc] + red[2][rr][cc] + red[3][rr][cc];
    val += bo[cc] + node[(r0 + rr) * DDIM + cc];
    // LN over the 128 cols of row rr (threads t in [rr*128, rr*128+128) = waves 2rr,2rr+1)
    float vsum = val, vsq = val * val;
#pragma unroll
    for (int off = 32; off >= 1; off >>= 1) {
        vsum += __shfl_down(vsum, off);
        vsq  += __shfl_down(vsq, off);
    }
    if ((t & 63) == 0) sc2[t >> 6] = make_float2(vsum, vsq);
    __syncthreads();
    float sum = sc2[2 * rr].x + sc2[2 * rr + 1].x;
    float sq  = sc2[2 * rr].y + sc2[2 * rr + 1].y;
    float mu = sum * (1.0f / DDIM);
    float var = sq * (1.0f / DDIM) - mu * mu;
    x1[(r0 + rr) * DDIM + cc] = (val - mu) * rsqrtf(var + EPSV) * g1[cc] + b1[cc];
}

// ---------------- FFN layer 1: relu(x1 @ W1 + bf1), c = t spans 512 cols ----------------
__global__ __launch_bounds__(512) void k_ffn1(float* hidden, const float* x1, fp_c W1, fp_c bf1) {
    __shared__ float sx[4][DDIM];
    int t = threadIdx.x;
    int r0 = blockIdx.x * 4;
    sx[t >> 7][t & 127] = x1[r0 * DDIM + t];
    __syncthreads();
    float acc[4] = {0, 0, 0, 0};
#pragma unroll 8
    for (int k = 0; k < DDIM; k++) {
        float w = W1[k * FFN + t];
#pragma unroll
        for (int r = 0; r < 4; r++) acc[r] += sx[r][k] * w;
    }
    float b = bf1[t];
#pragma unroll
    for (int r = 0; r < 4; r++)
        hidden[(r0 + r) * FFN + t] = fmaxf(acc[r] + b, 0.f);
}

// ---------------- FFN layer 2 + residual + LN2 ----------------
__global__ __launch_bounds__(512) void k_ffn2_ln(float* out, const float* hidden,
                                                 const float* x1, fp_c W2, fp_c bf2, fp_c g2, fp_c b2) {
    __shared__ float sh[4][FFN];
    __shared__ float red[4][4][DDIM];
    __shared__ float2 sc2[8];
    int t = threadIdx.x;
    int r0 = blockIdx.x * 4;
    int c = t & 127;
    int ks = t >> 7;
#pragma unroll
    for (int idx = t, u = 0; u < 4; u++, idx += 512)
        sh[idx >> 9][idx & 511] = hidden[r0 * FFN + idx];
    __syncthreads();
    float acc[4] = {0, 0, 0, 0};
    int kbeg = ks * 128;
#pragma unroll 8
    for (int k = kbeg; k < kbeg + 128; k++) {
        float w = W2[k * DDIM + c];
#pragma unroll
        for (int r = 0; r < 4; r++) acc[r] += sh[r][k] * w;
    }
#pragma unroll
    for (int r = 0; r < 4; r++) red[ks][r][c] = acc[r];
    __syncthreads();
    int rr = t >> 7, cc = t & 127;
    float val = red[0][rr][cc] + red[1][rr][cc] + red[2][rr][cc] + red[3][rr][cc];
    val += bf2[cc] + x1[(r0 + rr) * DDIM + cc];
    float vsum = val, vsq = val * val;
#pragma unroll
    for (int off = 32; off >= 1; off >>= 1) {
        vsum += __shfl_down(vsum, off);
        vsq  += __shfl_down(vsq, off);
    }
    if ((t & 63) == 0) sc2[t >> 6] = make_float2(vsum, vsq);
    __syncthreads();
    float sum = sc2[2 * rr].x + sc2[2 * rr + 1].x;
    float sq  = sc2[2 * rr].y + sc2[2 * rr + 1].y;
    float mu = sum * (1.0f / DDIM);
    float var = sq * (1.0f / DDIM) - mu * mu;
    out[(r0 + rr) * DDIM + cc] = (val - mu) * rsqrtf(var + EPSV) * g2[cc] + b2[cc];
}

extern "C" void kernel_launch(void* const* d_in, const int* in_sizes, int n_in,
                              void* d_out, int out_size, void* d_ws, size_t ws_size,
                              hipStream_t stream) {
    fp_c node = (fp_c)d_in[0];
    fp_c edge_feat = (fp_c)d_in[1];
    const int* src = (const int*)d_in[2];
    const int* dst = (const int*)d_in[3];
    fp_c Wq = (fp_c)d_in[4];  fp_c bq = (fp_c)d_in[5];
    fp_c Wk = (fp_c)d_in[6];  fp_c bk = (fp_c)d_in[7];
    fp_c Wv = (fp_c)d_in[8];  fp_c bv = (fp_c)d_in[9];
    fp_c Wo = (fp_c)d_in[10]; fp_c bo = (fp_c)d_in[11];
    fp_c We = (fp_c)d_in[12]; fp_c be = (fp_c)d_in[13];
    fp_c g1 = (fp_c)d_in[14]; fp_c b1n = (fp_c)d_in[15];
    fp_c g2 = (fp_c)d_in[16]; fp_c b2n = (fp_c)d_in[17];
    fp_c W1 = (fp_c)d_in[18]; fp_c bf1 = (fp_c)d_in[19];
    fp_c W2 = (fp_c)d_in[20]; fp_c bf2 = (fp_c)d_in[21];

    char* ws = (char*)d_ws;
    int* flag     = (int*)ws;   ws += 16;
    int* eid      = (int*)ws;   ws += (size_t)NN * NN * 4;
    float* eb     = (float*)ws; ws += (size_t)NEDGE * 8 * 4;
    float* Qf     = (float*)ws; ws += (size_t)NN * DDIM * 4;
    float* Kf     = (float*)ws; ws += (size_t)NN * DDIM * 4;
    float* Vf     = (float*)ws; ws += (size_t)NN * DDIM * 4;
    float* attn_o = (float*)ws; ws += (size_t)NN * DDIM * 4;
    float* x1     = (float*)ws; ws += (size_t)NN * DDIM * 4;
    float* hidden = (float*)ws; ws += (size_t)NN * FFN * 4;

    k_detect<<<1, 64, 0, stream>>>(flag, src);
    k_init<<<2048, 256, 0, stream>>>(eid);
    k_scatter<<<(NEDGE + NN + 255) / 256, 256, 0, stream>>>(eid, src, dst, flag);
    k_ebias<<<NEDGE / 256, 256, 0, stream>>>(eb, edge_feat, We, be);
    k_qkv<<<NN / 4, 512, 0, stream>>>(Qf, Kf, Vf, node, Wq, bq, Wk, bk, Wv, bv);
    k_attn<<<NN, 64, 0, stream>>>(attn_o, Qf, Kf, Vf, eid, eb);
    k_proj_ln<<<NN / 4, 512, 0, stream>>>(x1, attn_o, Wo, bo, node, g1, b1n);
    k_ffn1<<<NN / 4, 512, 0, stream>>>(hidden, x1, W1, bf1);
    k_ffn2_ln<<<NN / 4, 512, 0, stream>>>((float*)d_out, hidden, x1, W2, bf2, g2, b2n);
}

// Round 4
// 92.901 us; speedup vs baseline: 1.6626x; 1.2625x over previous
//
#include <hip/hip_runtime.h>
#include <hip/hip_bf16.h>

#define NN   2048
#define DDIM 128
#define HH   8
#define DHH  16
#define NEDGE 65536
#define FFN  512
#define EPSV 1e-5f
#define CAP  256

typedef const float* fp_c;

// int64 vs int32 index layout: int64 values < 2048 have all-zero odd words.
__device__ __forceinline__ bool idx64(const int* src) {
    return (src[1] | src[3] | src[5] | src[7] | src[9] | src[11]) == 0;
}

// ---------------- prep: bitmap clear + eid=-2 at edge/diag cells + edge-bias GEMM ----------------
// All plain stores (races write identical values). Must precede k_scatter.
__global__ __launch_bounds__(256) void k_prep(int* eid, unsigned* bm, float* eb,
                                              const int* src, const int* dst,
                                              fp_c edge_feat, fp_c We, fp_c be) {
    __shared__ float sWe[80];
    __shared__ float sbe[8];
    int t0 = threadIdx.x;
    if (t0 < 80) sWe[t0] = We[t0];
    if (t0 < 8)  sbe[t0] = be[t0];
    __syncthreads();
    int t = blockIdx.x * 256 + t0;
    bool is64 = idx64(src);
    if (t < NN * 64 / 4) ((int4*)bm)[t] = make_int4(0, 0, 0, 0);  // clear 512 KB bitmap
    if (t < NN) eid[t * NN + t] = -2;
    if (t < NEDGE) {
        int s = is64 ? src[2 * t] : src[t];
        int d = is64 ? dst[2 * t] : dst[t];
        eid[s * NN + d] = -2;
        eid[d * NN + s] = -2;
        float ef[10];
#pragma unroll
        for (int k = 0; k < 10; k++) ef[k] = edge_feat[t * 10 + k];
#pragma unroll
        for (int h = 0; h < 8; h++) {
            float a = sbe[h];
#pragma unroll
            for (int k = 0; k < 10; k++) a += ef[k] * sWe[k * 8 + h];
            eb[t * 8 + h] = a;
        }
    }
}

// ---------------- scatter: eid atomicMax (last-wins = max e) + adjacency bitmap ----------------
__global__ __launch_bounds__(256) void k_scatter(int* eid, unsigned* bm, const int* src, const int* dst) {
    int t = blockIdx.x * blockDim.x + threadIdx.x;
    bool is64 = idx64(src);
    if (t < NEDGE) {
        int s = is64 ? src[2 * t] : src[t];
        int d = is64 ? dst[2 * t] : dst[t];
        atomicMax(&eid[s * NN + d], t);
        atomicOr(&bm[s * 64 + (d >> 5)], 1u << (d & 31));
        atomicOr(&bm[d * 64 + (s >> 5)], 1u << (s & 31));
    } else if (t < NEDGE + NN) {
        int i = t - NEDGE;
        atomicOr(&bm[i * 64 + (i >> 5)], 1u << (i & 31));
    }
}

// ---------------- QKV: node[2048,128] @ {Wq,Wk,Wv}[128,128] ----------------
__global__ __launch_bounds__(512) void k_qkv(float* Qf, float* Kf, float* Vf, fp_c x,
                                             fp_c Wq, fp_c bq, fp_c Wk, fp_c bk, fp_c Wv, fp_c bv) {
    __shared__ float sx[4][DDIM];
    __shared__ float red[3][4][4][DDIM];
    int t = threadIdx.x;
    int r0 = blockIdx.x * 4;
    int c = t & 127;
    int ks = t >> 7;
    sx[t >> 7][t & 127] = x[r0 * DDIM + t];
    __syncthreads();
    float aq[4] = {0, 0, 0, 0}, ak[4] = {0, 0, 0, 0}, av[4] = {0, 0, 0, 0};
    int kbeg = ks * 32;
#pragma unroll 8
    for (int k = kbeg; k < kbeg + 32; k++) {
        float wq = Wq[k * DDIM + c];
        float wk = Wk[k * DDIM + c];
        float wv = Wv[k * DDIM + c];
#pragma unroll
        for (int r = 0; r < 4; r++) {
            float xv = sx[r][k];
            aq[r] += xv * wq; ak[r] += xv * wk; av[r] += xv * wv;
        }
    }
#pragma unroll
    for (int r = 0; r < 4; r++) {
        red[0][ks][r][c] = aq[r];
        red[1][ks][r][c] = ak[r];
        red[2][ks][r][c] = av[r];
    }
    __syncthreads();
    int rr = t >> 7, cc = t & 127;
    float vq = 0, vk = 0, vv = 0;
#pragma unroll
    for (int s = 0; s < 4; s++) {
        vq += red[0][s][rr][cc];
        vk += red[1][s][rr][cc];
        vv += red[2][s][rr][cc];
    }
    Qf[(r0 + rr) * DDIM + cc] = (vq + bq[cc]) * 0.25f;
    Kf[(r0 + rr) * DDIM + cc] = vk + bk[cc];
    Vf[(r0 + rr) * DDIM + cc] = vv + bv[cc];
}

// ---------------- sparse masked attention: bitmap compaction, one wave per row ----------------
__global__ __launch_bounds__(64) void k_attn(float* attn_out, const float* Qf, const float* Kf,
                                             const float* Vf, const int* eid, const float* eb,
                                             const unsigned* bm) {
    __shared__ float qrow[DDIM];
    __shared__ int   lj[CAP];
    __shared__ int   lev[CAP];
    __shared__ float sc[CAP][HH];
    __shared__ float hinv[HH];
    int i = blockIdx.x;
    int lane = threadIdx.x;
    qrow[lane]      = Qf[i * DDIM + lane];
    qrow[lane + 64] = Qf[i * DDIM + lane + 64];

    // phase 1: bitmap -> compacted neighbor list (ascending j)
    unsigned word = bm[i * 64 + lane];
    int pc = __popc(word);
    int x = pc;
#pragma unroll
    for (int off = 1; off < 64; off <<= 1) {
        int y = __shfl_up(x, off);
        if (lane >= off) x += y;
    }
    int cnt = __shfl(x, 63);
    int idx = x - pc;
    unsigned w = word;
    while (w) {
        int b = __ffs(w) - 1;
        lj[idx++] = (lane << 5) + b;
        w &= w - 1;
    }
    if (lane < 8) lj[cnt + lane] = 0;  // pad
    __syncthreads();
    int cnt8 = (cnt + 7) & ~7;
    // gather edge-id (bias index) at neighbor cells; pads get -2
    for (int n = lane; n < cnt8; n += 64)
        lev[n] = (n < cnt) ? eid[(long)i * NN + lj[n]] : -2;
    __syncthreads();

    // phase 2: scores (lane = nsub*8 + h), unconditional padded loop
    int h = lane & 7;
    int nsub = lane >> 3;
    const float4* q4 = (const float4*)(qrow + h * DHH);
    float4 q0 = q4[0], q1 = q4[1], q2 = q4[2], q3 = q4[3];
#pragma unroll 2
    for (int n = nsub; n < cnt8; n += 8) {
        int j = lj[n];
        const float4* k4 = (const float4*)(Kf + j * DDIM + h * DHH);
        float4 k0 = k4[0], k1 = k4[1], k2 = k4[2], k3 = k4[3];
        float s = q0.x * k0.x + q0.y * k0.y + q0.z * k0.z + q0.w * k0.w
                + q1.x * k1.x + q1.y * k1.y + q1.z * k1.z + q1.w * k1.w
                + q2.x * k2.x + q2.y * k2.y + q2.z * k2.z + q2.w * k2.w
                + q3.x * k3.x + q3.y * k3.y + q3.z * k3.z + q3.w * k3.w;
        int ev = lev[n];
        if (ev >= 0) s += eb[ev * 8 + h];
        sc[n][h] = s;
    }
    __syncthreads();

    // phase 3: per-head softmax (8 contiguous lanes per head)
    {
        int hh = lane >> 3;
        int sub = lane & 7;
        float m = -1e30f;
        for (int n = sub; n < cnt; n += 8) m = fmaxf(m, sc[n][hh]);
#pragma unroll
        for (int off = 1; off < 8; off <<= 1) m = fmaxf(m, __shfl_xor(m, off));
        float ssum = 0.f;
        for (int n = sub; n < cnt; n += 8) {
            float e = __expf(sc[n][hh] - m);
            sc[n][hh] = e;
            ssum += e;
        }
#pragma unroll
        for (int off = 1; off < 8; off <<= 1) ssum += __shfl_xor(ssum, off);
        if (sub == 0) hinv[hh] = 1.0f / ssum;
    }
    // zero the pad rows so PV can run unconditionally
    {
        int n = cnt + nsub;
        if (n < cnt8) sc[n][h] = 0.f;
    }
    __syncthreads();

    // phase 4: PV — float2 per lane, coalesced V rows
    int c0 = lane * 2;
    int h2 = lane >> 3;
    float a0 = 0.f, a1 = 0.f;
#pragma unroll 2
    for (int n = 0; n < cnt8; n++) {
        int j = lj[n];
        float2 v = *(const float2*)(Vf + j * DDIM + c0);
        float p = sc[n][h2];
        a0 += p * v.x;
        a1 += p * v.y;
    }
    float inv = hinv[h2];
    *(float2*)(attn_out + i * DDIM + c0) = make_float2(a0 * inv, a1 * inv);
}

// ---------------- Wo proj + bias + residual + LN1 ----------------
__global__ __launch_bounds__(512) void k_proj_ln(float* x1, const float* ain, fp_c Wo, fp_c bo,
                                                 fp_c node, fp_c g1, fp_c b1) {
    __shared__ float sx[4][DDIM];
    __shared__ float red[4][4][DDIM];
    __shared__ float2 sc2[8];
    int t = threadIdx.x;
    int r0 = blockIdx.x * 4;
    int c = t & 127;
    int ks = t >> 7;
    sx[t >> 7][t & 127] = ain[r0 * DDIM + t];
    __syncthreads();
    float acc[4] = {0, 0, 0, 0};
    int kbeg = ks * 32;
#pragma unroll 8
    for (int k = kbeg; k < kbeg + 32; k++) {
        float w = Wo[k * DDIM + c];
#pragma unroll
        for (int r = 0; r < 4; r++) acc[r] += sx[r][k] * w;
    }
#pragma unroll
    for (int r = 0; r < 4; r++) red[ks][r][c] = acc[r];
    __syncthreads();
    int rr = t >> 7, cc = t & 127;
    float val = red[0][rr][cc] + red[1][rr][cc] + red[2][rr][cc] + red[3][rr][cc];
    val += bo[cc] + node[(r0 + rr) * DDIM + cc];
    float vsum = val, vsq = val * val;
#pragma unroll
    for (int off = 32; off >= 1; off >>= 1) {
        vsum += __shfl_down(vsum, off);
        vsq  += __shfl_down(vsq, off);
    }
    if ((t & 63) == 0) sc2[t >> 6] = make_float2(vsum, vsq);
    __syncthreads();
    float sum = sc2[2 * rr].x + sc2[2 * rr + 1].x;
    float sq  = sc2[2 * rr].y + sc2[2 * rr + 1].y;
    float mu = sum * (1.0f / DDIM);
    float var = sq * (1.0f / DDIM) - mu * mu;
    x1[(r0 + rr) * DDIM + cc] = (val - mu) * rsqrtf(var + EPSV) * g1[cc] + b1[cc];
}

// ---------------- FFN layer 1: relu(x1 @ W1 + bf1) ----------------
__global__ __launch_bounds__(512) void k_ffn1(float* hidden, const float* x1, fp_c W1, fp_c bf1) {
    __shared__ float sx[4][DDIM];
    int t = threadIdx.x;
    int r0 = blockIdx.x * 4;
    sx[t >> 7][t & 127] = x1[r0 * DDIM + t];
    __syncthreads();
    float acc[4] = {0, 0, 0, 0};
#pragma unroll 8
    for (int k = 0; k < DDIM; k++) {
        float w = W1[k * FFN + t];
#pragma unroll
        for (int r = 0; r < 4; r++) acc[r] += sx[r][k] * w;
    }
    float b = bf1[t];
#pragma unroll
    for (int r = 0; r < 4; r++)
        hidden[(r0 + r) * FFN + t] = fmaxf(acc[r] + b, 0.f);
}

// ---------------- FFN layer 2 + residual + LN2 ----------------
__global__ __launch_bounds__(512) void k_ffn2_ln(float* out, const float* hidden,
                                                 const float* x1, fp_c W2, fp_c bf2, fp_c g2, fp_c b2) {
    __shared__ float sh[4][FFN];
    __shared__ float red[4][4][DDIM];
    __shared__ float2 sc2[8];
    int t = threadIdx.x;
    int r0 = blockIdx.x * 4;
    int c = t & 127;
    int ks = t >> 7;
#pragma unroll
    for (int idx = t, u = 0; u < 4; u++, idx += 512)
        sh[idx >> 9][idx & 511] = hidden[r0 * FFN + idx];
    __syncthreads();
    float acc[4] = {0, 0, 0, 0};
    int kbeg = ks * 128;
#pragma unroll 8
    for (int k = kbeg; k < kbeg + 128; k++) {
        float w = W2[k * DDIM + c];
#pragma unroll
        for (int r = 0; r < 4; r++) acc[r] += sh[r][k] * w;
    }
#pragma unroll
    for (int r = 0; r < 4; r++) red[ks][r][c] = acc[r];
    __syncthreads();
    int rr = t >> 7, cc = t & 127;
    float val = red[0][rr][cc] + red[1][rr][cc] + red[2][rr][cc] + red[3][rr][cc];
    val += bf2[cc] + x1[(r0 + rr) * DDIM + cc];
    float vsum = val, vsq = val * val;
#pragma unroll
    for (int off = 32; off >= 1; off >>= 1) {
        vsum += __shfl_down(vsum, off);
        vsq  += __shfl_down(vsq, off);
    }
    if ((t & 63) == 0) sc2[t >> 6] = make_float2(vsum, vsq);
    __syncthreads();
    float sum = sc2[2 * rr].x + sc2[2 * rr + 1].x;
    float sq  = sc2[2 * rr].y + sc2[2 * rr + 1].y;
    float mu = sum * (1.0f / DDIM);
    float var = sq * (1.0f / DDIM) - mu * mu;
    out[(r0 + rr) * DDIM + cc] = (val - mu) * rsqrtf(var + EPSV) * g2[cc] + b2[cc];
}

extern "C" void kernel_launch(void* const* d_in, const int* in_sizes, int n_in,
                              void* d_out, int out_size, void* d_ws, size_t ws_size,
                              hipStream_t stream) {
    fp_c node = (fp_c)d_in[0];
    fp_c edge_feat = (fp_c)d_in[1];
    const int* src = (const int*)d_in[2];
    const int* dst = (const int*)d_in[3];
    fp_c Wq = (fp_c)d_in[4];  fp_c bq = (fp_c)d_in[5];
    fp_c Wk = (fp_c)d_in[6];  fp_c bk = (fp_c)d_in[7];
    fp_c Wv = (fp_c)d_in[8];  fp_c bv = (fp_c)d_in[9];
    fp_c Wo = (fp_c)d_in[10]; fp_c bo = (fp_c)d_in[11];
    fp_c We = (fp_c)d_in[12]; fp_c be = (fp_c)d_in[13];
    fp_c g1 = (fp_c)d_in[14]; fp_c b1n = (fp_c)d_in[15];
    fp_c g2 = (fp_c)d_in[16]; fp_c b2n = (fp_c)d_in[17];
    fp_c W1 = (fp_c)d_in[18]; fp_c bf1 = (fp_c)d_in[19];
    fp_c W2 = (fp_c)d_in[20]; fp_c bf2 = (fp_c)d_in[21];

    char* ws = (char*)d_ws;
    int* eid      = (int*)ws;      ws += (size_t)NN * NN * 4;
    unsigned* bm  = (unsigned*)ws; ws += (size_t)NN * 64 * 4;
    float* eb     = (float*)ws;    ws += (size_t)NEDGE * 8 * 4;
    float* Qf     = (float*)ws;    ws += (size_t)NN * DDIM * 4;
    float* Kf     = (float*)ws;    ws += (size_t)NN * DDIM * 4;
    float* Vf     = (float*)ws;    ws += (size_t)NN * DDIM * 4;
    float* attn_o = (float*)ws;    ws += (size_t)NN * DDIM * 4;
    float* x1     = (float*)ws;    ws += (size_t)NN * DDIM * 4;
    float* hidden = (float*)ws;    ws += (size_t)NN * FFN * 4;

    k_prep<<<NEDGE / 256, 256, 0, stream>>>(eid, bm, eb, src, dst, edge_feat, We, be);
    k_scatter<<<(NEDGE + NN + 255) / 256, 256, 0, stream>>>(eid, bm, src, dst);
    k_qkv<<<NN / 4, 512, 0, stream>>>(Qf, Kf, Vf, node, Wq, bq, Wk, bk, Wv, bv);
    k_attn<<<NN, 64, 0, stream>>>(attn_o, Qf, Kf, Vf, eid, eb, bm);
    k_proj_ln<<<NN / 4, 512, 0, stream>>>(x1, attn_o, Wo, bo, node, g1, b1n);
    k_ffn1<<<NN / 4, 512, 0, stream>>>(hidden, x1, W1, bf1);
    k_ffn2_ln<<<NN / 4, 512, 0, stream>>>((float*)d_out, hidden, x1, W2, bf2, g2, b2n);
}

// Round 5
// 68.379 us; speedup vs baseline: 2.2589x; 1.3586x over previous
//
#include <hip/hip_runtime.h>
#include <hip/hip_bf16.h>

#define NN   2048
#define DDIM 128
#define HH   8
#define DHH  16
#define NEDGE 65536
#define FFN  512
#define EPSV 1e-5f
#define CAP  256

typedef const float* fp_c;

// int64 vs int32 index layout: int64 values < 2048 have all-zero odd words.
__device__ __forceinline__ bool idx64(const int* src) {
    return (src[1] | src[3] | src[5] | src[7] | src[9] | src[11]) == 0;
}

// ================= fused prep + QKV =================
// blocks 0..511: QKV GEMM rows 4b..4b+3.  blocks 512..767: prep (bitmap clear,
// eid=-2 at edge/diag cells, edge-bias mini-GEMM). Independent buffers.
__global__ __launch_bounds__(512) void k_pq(float* Qf, float* Kf, float* Vf, fp_c x,
                                            fp_c Wq, fp_c bq, fp_c Wk, fp_c bk, fp_c Wv, fp_c bv,
                                            int* eid, unsigned* bm, float* eb,
                                            const int* src, const int* dst,
                                            fp_c edge_feat, fp_c We, fp_c be) {
    int b = blockIdx.x;
    int t = threadIdx.x;
    if (b < 512) {
        __shared__ float sx[4][DDIM];
        __shared__ float red[3][4][4][DDIM];
        int r0 = b * 4;
        int c = t & 127;
        int ks = t >> 7;
        sx[t >> 7][t & 127] = x[r0 * DDIM + t];
        __syncthreads();
        float aq[4] = {0, 0, 0, 0}, ak[4] = {0, 0, 0, 0}, av[4] = {0, 0, 0, 0};
        int kbeg = ks * 32;
#pragma unroll 8
        for (int k = kbeg; k < kbeg + 32; k++) {
            float wq = Wq[k * DDIM + c];
            float wk = Wk[k * DDIM + c];
            float wv = Wv[k * DDIM + c];
#pragma unroll
            for (int r = 0; r < 4; r++) {
                float xv = sx[r][k];
                aq[r] += xv * wq; ak[r] += xv * wk; av[r] += xv * wv;
            }
        }
#pragma unroll
        for (int r = 0; r < 4; r++) {
            red[0][ks][r][c] = aq[r];
            red[1][ks][r][c] = ak[r];
            red[2][ks][r][c] = av[r];
        }
        __syncthreads();
        int rr = t >> 7, cc = t & 127;
        float vq = 0, vk = 0, vv = 0;
#pragma unroll
        for (int s = 0; s < 4; s++) {
            vq += red[0][s][rr][cc];
            vk += red[1][s][rr][cc];
            vv += red[2][s][rr][cc];
        }
        Qf[(r0 + rr) * DDIM + cc] = (vq + bq[cc]) * 0.25f;
        Kf[(r0 + rr) * DDIM + cc] = vk + bk[cc];
        Vf[(r0 + rr) * DDIM + cc] = vv + bv[cc];
    } else {
        __shared__ float sWe[80];
        __shared__ float sbe[8];
        if (t < 80) sWe[t] = We[t];
        if (t < 8)  sbe[t] = be[t];
        __syncthreads();
        int u = (b - 512) * 512 + t;
        bool is64 = idx64(src);
        if (u < NN * 64 / 4) ((int4*)bm)[u] = make_int4(0, 0, 0, 0);
        if (u < NN) eid[u * NN + u] = -2;
        if (u < NEDGE) {
            int s = is64 ? src[2 * u] : src[u];
            int d = is64 ? dst[2 * u] : dst[u];
            eid[s * NN + d] = -2;
            eid[d * NN + s] = -2;
            float ef[10];
#pragma unroll
            for (int k = 0; k < 10; k++) ef[k] = edge_feat[u * 10 + k];
#pragma unroll
            for (int h = 0; h < 8; h++) {
                float a = sbe[h];
#pragma unroll
                for (int k = 0; k < 10; k++) a += ef[k] * sWe[k * 8 + h];
                eb[u * 8 + h] = a;
            }
        }
    }
}

// ---------------- scatter: eid atomicMax (last-wins = max e) + adjacency bitmap ----------------
__global__ __launch_bounds__(512) void k_scatter(int* eid, unsigned* bm, const int* src, const int* dst) {
    int t = blockIdx.x * blockDim.x + threadIdx.x;
    bool is64 = idx64(src);
    if (t < NEDGE) {
        int s = is64 ? src[2 * t] : src[t];
        int d = is64 ? dst[2 * t] : dst[t];
        atomicMax(&eid[s * NN + d], t);
        atomicOr(&bm[s * 64 + (d >> 5)], 1u << (d & 31));
        atomicOr(&bm[d * 64 + (s >> 5)], 1u << (s & 31));
    } else if (t < NEDGE + NN) {
        int i = t - NEDGE;
        atomicOr(&bm[i * 64 + (i >> 5)], 1u << (i & 31));
    }
}

// ---------------- sparse masked attention: 256 threads (4 waves) per row ----------------
__global__ __launch_bounds__(256) void k_attn(float* attn_out, const float* Qf, const float* Kf,
                                              const float* Vf, const int* eid, const float* eb,
                                              const unsigned* bm) {
    __shared__ float qrow[DDIM];
    __shared__ int   lj[CAP + 8];
    __shared__ int   lev[CAP + 8];
    __shared__ float sc[CAP + 8][HH];
    __shared__ float hinv[HH];
    __shared__ float redpv[2][DDIM];
    __shared__ int   scnt;
    int i = blockIdx.x;
    int t = threadIdx.x;
    if (t < 128) qrow[t] = Qf[i * DDIM + t];

    // phase 1 (wave 0): bitmap -> compacted neighbor list (ascending j)
    if (t < 64) {
        unsigned word = bm[i * 64 + t];
        int pc = __popc(word);
        int x = pc;
#pragma unroll
        for (int off = 1; off < 64; off <<= 1) {
            int y = __shfl_up(x, off);
            if (t >= off) x += y;
        }
        int cnt = __shfl(x, 63);
        if (cnt > CAP - 8) cnt = CAP - 8;
        int idx = x - pc;
        unsigned w = word;
        while (w && idx < CAP) {
            int bpos = __ffs(w) - 1;
            lj[idx++] = (t << 5) + bpos;
            w &= w - 1;
        }
        if (t < 8) lj[cnt + t] = 0;  // pad slots
        if (t == 0) scnt = cnt;
    }
    __syncthreads();
    int cnt = scnt;
    int cnt8 = (cnt + 7) & ~7;
    if (t < cnt8) lev[t] = (t < cnt) ? eid[(long)i * NN + lj[t]] : -2;
    __syncthreads();

    // phase 2: scores — 32 neighbor slots x 8 heads in parallel
    int h = t & 7;
    int nsl = t >> 3;
    const float4* q4 = (const float4*)(qrow + h * DHH);
    float4 q0 = q4[0], q1 = q4[1], q2 = q4[2], q3 = q4[3];
    for (int n = nsl; n < cnt8; n += 32) {
        int j = lj[n];
        const float4* k4 = (const float4*)(Kf + j * DDIM + h * DHH);
        float4 k0 = k4[0], k1 = k4[1], k2 = k4[2], k3 = k4[3];
        float s = q0.x * k0.x + q0.y * k0.y + q0.z * k0.z + q0.w * k0.w
                + q1.x * k1.x + q1.y * k1.y + q1.z * k1.z + q1.w * k1.w
                + q2.x * k2.x + q2.y * k2.y + q2.z * k2.z + q2.w * k2.w
                + q3.x * k3.x + q3.y * k3.y + q3.z * k3.z + q3.w * k3.w;
        int ev = lev[n];
        if (ev >= 0) s += eb[ev * 8 + h];
        sc[n][h] = s;
    }
    __syncthreads();

    // phase 3: per-head softmax — 32 threads per head
    {
        int hh = t >> 5;
        int sub = t & 31;
        float m = -1e30f;
        for (int n = sub; n < cnt; n += 32) m = fmaxf(m, sc[n][hh]);
#pragma unroll
        for (int off = 1; off < 32; off <<= 1) m = fmaxf(m, __shfl_xor(m, off));
        float ssum = 0.f;
        for (int n = sub; n < cnt; n += 32) {
            float e = __expf(sc[n][hh] - m);
            sc[n][hh] = e;
            ssum += e;
        }
#pragma unroll
        for (int off = 1; off < 32; off <<= 1) ssum += __shfl_xor(ssum, off);
        if (sub == 0) hinv[hh] = 1.0f / ssum;
    }
    // zero pad rows (<=7 rows x 8 heads, threads 0..63)
    if (t < 64) {
        int p = cnt + (t >> 3);
        if (p < cnt8) sc[p][t & 7] = 0.f;
    }
    __syncthreads();

    // phase 4: PV — neighbors split across 2 groups of 128 threads
    {
        int g = t >> 7, c = t & 127, h2 = c >> 4;
        float a = 0.f;
#pragma unroll 4
        for (int n = g; n < cnt8; n += 2)
            a += sc[n][h2] * Vf[lj[n] * DDIM + c];
        redpv[g][c] = a;
    }
    __syncthreads();
    if (t < 128)
        attn_out[i * DDIM + t] = (redpv[0][t] + redpv[1][t]) * hinv[t >> 4];
}

// ================= fused tail: Wo+LN1 -> FFN1 -> FFN2+LN2 =================
// Block b owns rows 4b..4b+3; x1 and hidden live in LDS only.
__global__ __launch_bounds__(512) void k_tail(float* out, const float* ain,
                                              fp_c Wo, fp_c bo, fp_c node, fp_c g1, fp_c b1,
                                              fp_c W1, fp_c bf1, fp_c W2, fp_c bf2,
                                              fp_c g2, fp_c b2) {
    __shared__ float sa[4][DDIM];
    __shared__ float red[4][4][DDIM];
    __shared__ float x1ld[4][DDIM];
    __shared__ float sh[4][FFN];
    __shared__ float2 sc2[8];
    int t = threadIdx.x;
    int r0 = blockIdx.x * 4;
    int c = t & 127;
    int ks = t >> 7;
    int rr = t >> 7, cc = t & 127;
    sa[t >> 7][t & 127] = ain[r0 * DDIM + t];
    __syncthreads();

    // phase A: Wo proj (K-split 4) + bias + residual + LN1 -> x1ld
    {
        float acc[4] = {0, 0, 0, 0};
        int kbeg = ks * 32;
#pragma unroll 8
        for (int k = kbeg; k < kbeg + 32; k++) {
            float w = Wo[k * DDIM + c];
#pragma unroll
            for (int r = 0; r < 4; r++) acc[r] += sa[r][k] * w;
        }
#pragma unroll
        for (int r = 0; r < 4; r++) red[ks][r][c] = acc[r];
        __syncthreads();
        float val = red[0][rr][cc] + red[1][rr][cc] + red[2][rr][cc] + red[3][rr][cc];
        val += bo[cc] + node[(r0 + rr) * DDIM + cc];
        float vs = val, vq = val * val;
#pragma unroll
        for (int off = 32; off >= 1; off >>= 1) {
            vs += __shfl_down(vs, off);
            vq += __shfl_down(vq, off);
        }
        if ((t & 63) == 0) sc2[t >> 6] = make_float2(vs, vq);
        __syncthreads();
        float sum = sc2[2 * rr].x + sc2[2 * rr + 1].x;
        float sq  = sc2[2 * rr].y + sc2[2 * rr + 1].y;
        float mu = sum * (1.0f / DDIM);
        float var = sq * (1.0f / DDIM) - mu * mu;
        x1ld[rr][cc] = (val - mu) * rsqrtf(var + EPSV) * g1[cc] + b1[cc];
    }
    __syncthreads();

    // phase B: hidden = relu(x1 @ W1 + bf1), column t of 512
    {
        float acc[4] = {0, 0, 0, 0};
#pragma unroll 8
        for (int k = 0; k < DDIM; k++) {
            float w = W1[k * FFN + t];
#pragma unroll
            for (int r = 0; r < 4; r++) acc[r] += x1ld[r][k] * w;
        }
        float bb = bf1[t];
#pragma unroll
        for (int r = 0; r < 4; r++) sh[r][t] = fmaxf(acc[r] + bb, 0.f);
    }
    __syncthreads();

    // phase C: ffn2 (K-split 4 over 512) + bias + residual + LN2 -> out
    {
        float acc[4] = {0, 0, 0, 0};
        int kbeg = ks * 128;
#pragma unroll 8
        for (int k = kbeg; k < kbeg + 128; k++) {
            float w = W2[k * DDIM + c];
#pragma unroll
            for (int r = 0; r < 4; r++) acc[r] += sh[r][k] * w;
        }
#pragma unroll
        for (int r = 0; r < 4; r++) red[ks][r][c] = acc[r];
        __syncthreads();
        float val = red[0][rr][cc] + red[1][rr][cc] + red[2][rr][cc] + red[3][rr][cc];
        val += bf2[cc] + x1ld[rr][cc];
        float vs = val, vq = val * val;
#pragma unroll
        for (int off = 32; off >= 1; off >>= 1) {
            vs += __shfl_down(vs, off);
            vq += __shfl_down(vq, off);
        }
        if ((t & 63) == 0) sc2[t >> 6] = make_float2(vs, vq);
        __syncthreads();
        float sum = sc2[2 * rr].x + sc2[2 * rr + 1].x;
        float sq  = sc2[2 * rr].y + sc2[2 * rr + 1].y;
        float mu = sum * (1.0f / DDIM);
        float var = sq * (1.0f / DDIM) - mu * mu;
        out[(r0 + rr) * DDIM + cc] = (val - mu) * rsqrtf(var + EPSV) * g2[cc] + b2[cc];
    }
}

extern "C" void kernel_launch(void* const* d_in, const int* in_sizes, int n_in,
                              void* d_out, int out_size, void* d_ws, size_t ws_size,
                              hipStream_t stream) {
    fp_c node = (fp_c)d_in[0];
    fp_c edge_feat = (fp_c)d_in[1];
    const int* src = (const int*)d_in[2];
    const int* dst = (const int*)d_in[3];
    fp_c Wq = (fp_c)d_in[4];  fp_c bq = (fp_c)d_in[5];
    fp_c Wk = (fp_c)d_in[6];  fp_c bk = (fp_c)d_in[7];
    fp_c Wv = (fp_c)d_in[8];  fp_c bv = (fp_c)d_in[9];
    fp_c Wo = (fp_c)d_in[10]; fp_c bo = (fp_c)d_in[11];
    fp_c We = (fp_c)d_in[12]; fp_c be = (fp_c)d_in[13];
    fp_c g1 = (fp_c)d_in[14]; fp_c b1n = (fp_c)d_in[15];
    fp_c g2 = (fp_c)d_in[16]; fp_c b2n = (fp_c)d_in[17];
    fp_c W1 = (fp_c)d_in[18]; fp_c bf1 = (fp_c)d_in[19];
    fp_c W2 = (fp_c)d_in[20]; fp_c bf2 = (fp_c)d_in[21];

    char* ws = (char*)d_ws;
    int* eid      = (int*)ws;      ws += (size_t)NN * NN * 4;
    unsigned* bm  = (unsigned*)ws; ws += (size_t)NN * 64 * 4;
    float* eb     = (float*)ws;    ws += (size_t)NEDGE * 8 * 4;
    float* Qf     = (float*)ws;    ws += (size_t)NN * DDIM * 4;
    float* Kf     = (float*)ws;    ws += (size_t)NN * DDIM * 4;
    float* Vf     = (float*)ws;    ws += (size_t)NN * DDIM * 4;
    float* attn_o = (float*)ws;    ws += (size_t)NN * DDIM * 4;

    k_pq<<<768, 512, 0, stream>>>(Qf, Kf, Vf, node, Wq, bq, Wk, bk, Wv, bv,
                                  eid, bm, eb, src, dst, edge_feat, We, be);
    k_scatter<<<(NEDGE + NN + 511) / 512, 512, 0, stream>>>(eid, bm, src, dst);
    k_attn<<<NN, 256, 0, stream>>>(attn_o, Qf, Kf, Vf, eid, eb, bm);
    k_tail<<<NN / 4, 512, 0, stream>>>((float*)d_out, attn_o, Wo, bo, node, g1, b1n,
                                       W1, bf1, W2, bf2, g2, b2n);
}